// Round 1
// baseline (556.620 us; speedup 1.0000x reference)
//
#include <hip/hip_runtime.h>

// ---------------- QR: 3x3 Householder, LAPACK sgeqrf/sorgqr convention ----------------
__device__ inline void qr3_q(const double A[3][3], double Q[3][3]){
  double a[3][3];
#pragma unroll
  for (int r = 0; r < 3; r++)
#pragma unroll
    for (int c = 0; c < 3; c++) a[r][c] = A[r][c];

  double v1[3] = {1.0, 0.0, 0.0};
  double tau1 = 0.0;
  {
    double xn2 = a[1][0]*a[1][0] + a[2][0]*a[2][0];
    if (xn2 != 0.0){
      double alpha = a[0][0];
      double beta = -copysign(sqrt(alpha*alpha + xn2), alpha);
      tau1 = (beta - alpha) / beta;
      double inv = 1.0 / (alpha - beta);
      v1[1] = a[1][0] * inv;
      v1[2] = a[2][0] * inv;
#pragma unroll
      for (int c = 1; c < 3; c++){
        double w = a[0][c] + v1[1]*a[1][c] + v1[2]*a[2][c];
        double tw = tau1 * w;
        a[0][c] -= tw;
        a[1][c] -= tw * v1[1];
        a[2][c] -= tw * v1[2];
      }
    }
  }
  double tau2 = 0.0, v2 = 0.0;
  {
    double x2 = a[2][1];
    if (x2 != 0.0){
      double alpha = a[1][1];
      double beta = -copysign(sqrt(alpha*alpha + x2*x2), alpha);
      tau2 = (beta - alpha) / beta;
      v2 = x2 / (alpha - beta);
    }
  }
  // M = I - tau2 * u u^T with u = (0, 1, v2)
  double M[3][3] = {{1.0, 0.0, 0.0},
                    {0.0, 1.0 - tau2, -tau2*v2},
                    {0.0, -tau2*v2, 1.0 - tau2*v2*v2}};
  // Q = H1 * M = M - tau1 * v1 (v1^T M)
#pragma unroll
  for (int c = 0; c < 3; c++){
    double w = v1[0]*M[0][c] + v1[1]*M[1][c] + v1[2]*M[2][c];
#pragma unroll
    for (int r = 0; r < 3; r++)
      Q[r][c] = M[r][c] - tau1 * v1[r] * w;
  }
}

// ---------------- CSR build ----------------
__global__ void k_count(const int* __restrict__ dst, int E, int* __restrict__ deg){
  int e = blockIdx.x*256 + threadIdx.x;
  if (e < E) atomicAdd(&deg[dst[e]], 1);
}

__global__ void k_scanA(const int* __restrict__ deg, int N, int* __restrict__ start, int* __restrict__ bsum){
  __shared__ int s[1024];
  int t = threadIdx.x;
  int i = blockIdx.x*1024 + t;
  int v = (i < N) ? deg[i] : 0;
  s[t] = v;
  __syncthreads();
  for (int off = 1; off < 1024; off <<= 1){
    int add = (t >= off) ? s[t - off] : 0;
    __syncthreads();
    s[t] += add;
    __syncthreads();
  }
  if (i < N) start[i] = s[t] - v;        // block-local exclusive
  if (t == 1023) bsum[blockIdx.x] = s[t];
}

__global__ void k_scanB(int* __restrict__ bsum, int nb, int* __restrict__ start, int N){
  if (threadIdx.x == 0 && blockIdx.x == 0){
    int run = 0;
    for (int j = 0; j < nb; j++){ int tv = bsum[j]; bsum[j] = run; run += tv; }
    start[N] = run;
  }
}

__global__ void k_scanC(int* __restrict__ start, const int* __restrict__ bsum, int* __restrict__ cursor, int N){
  int i = blockIdx.x*256 + threadIdx.x;
  if (i < N){
    int v = start[i] + bsum[i >> 10];
    start[i] = v;
    cursor[i] = v;
  }
}

__global__ void k_fill(const int* __restrict__ src, const int* __restrict__ dst, int E,
                       int* __restrict__ cursor, int* __restrict__ csr){
  int e = blockIdx.x*256 + threadIdx.x;
  if (e < E){
    int p = atomicAdd(&cursor[dst[e]], 1);
    csr[p] = src[e];
  }
}

// ---------------- fp32 GEMM: H(Mx128) = X(Mx128) @ W(128x128) + bias ----------------
__launch_bounds__(256)
__global__ void k_gemm128(const float* __restrict__ X, const float* __restrict__ W,
                          const float* __restrict__ bias, float* __restrict__ H, int M){
  __shared__ float xs[32][132];   // xs[k][r], transposed tile
  __shared__ float ws[32][132];   // ws[k][c]
  const int tid = threadIdx.x;
  const int tx = tid & 15;        // 16 col-groups: cols tx*4..+3 and 64+tx*4..+3
  const int ty = tid >> 4;        // 16 row-groups: rows ty*4..+3 and 64+ty*4..+3
  const int r0 = blockIdx.x * 128;
  float acc[8][8] = {};
  for (int k0 = 0; k0 < 128; k0 += 32){
#pragma unroll
    for (int i = 0; i < 4; i++){
      int s = i*256 + tid;
      int kq = (s & 7) << 2;      // 0,4,...,28
      int r  = s >> 3;            // 0..127
      int gr = r0 + r;
      float4 v = make_float4(0.f, 0.f, 0.f, 0.f);
      if (gr < M) v = *(const float4*)(X + (size_t)gr*128 + k0 + kq);
      xs[kq+0][r] = v.x; xs[kq+1][r] = v.y; xs[kq+2][r] = v.z; xs[kq+3][r] = v.w;
    }
#pragma unroll
    for (int i = 0; i < 4; i++){
      int s = i*256 + tid;
      int c4 = (s & 31) << 2;
      int kk = s >> 5;
      *(float4*)&ws[kk][c4] = *(const float4*)(W + (size_t)(k0+kk)*128 + c4);
    }
    __syncthreads();
#pragma unroll 8
    for (int k = 0; k < 32; k++){
      float4 a0 = *(const float4*)&xs[k][ty << 2];
      float4 a1 = *(const float4*)&xs[k][(ty << 2) + 64];
      float4 b0 = *(const float4*)&ws[k][tx << 2];
      float4 b1 = *(const float4*)&ws[k][(tx << 2) + 64];
      float av[8] = {a0.x,a0.y,a0.z,a0.w,a1.x,a1.y,a1.z,a1.w};
      float bv[8] = {b0.x,b0.y,b0.z,b0.w,b1.x,b1.y,b1.z,b1.w};
#pragma unroll
      for (int ii = 0; ii < 8; ii++)
#pragma unroll
        for (int jj = 0; jj < 8; jj++)
          acc[ii][jj] = fmaf(av[ii], bv[jj], acc[ii][jj]);
    }
    __syncthreads();
  }
  float bv0[4], bv1[4];
#pragma unroll
  for (int j = 0; j < 4; j++){ bv0[j] = bias[(tx<<2)+j]; bv1[j] = bias[64+(tx<<2)+j]; }
#pragma unroll
  for (int ii = 0; ii < 8; ii++){
    int r = r0 + (ii < 4 ? (ty<<2) + ii : 64 + (ty<<2) + (ii - 4));
    if (r < M){
      float4 o0 = make_float4(acc[ii][0]+bv0[0], acc[ii][1]+bv0[1], acc[ii][2]+bv0[2], acc[ii][3]+bv0[3]);
      float4 o1 = make_float4(acc[ii][4]+bv1[0], acc[ii][5]+bv1[1], acc[ii][6]+bv1[2], acc[ii][7]+bv1[3]);
      *(float4*)(H + (size_t)r*128 + (tx<<2)) = o0;
      *(float4*)(H + (size_t)r*128 + 64 + (tx<<2)) = o1;
    }
  }
}

// ---------------- fused aggregation (CSR gather) + heads + QR + pos/R/t update ----------------
__launch_bounds__(256)
__global__ void k_agg(const float* __restrict__ H, const int* __restrict__ csr,
                      const int* __restrict__ start, float* __restrict__ Xout,
                      const float* __restrict__ Wc, const float* __restrict__ bc,
                      const float* __restrict__ WR, const float* __restrict__ bR,
                      const float* __restrict__ Wt, const float* __restrict__ bt,
                      const float* __restrict__ pos_in,
                      float* __restrict__ pos_o, float* __restrict__ R_o, float* __restrict__ t_o,
                      int layer, int N){
  const int wave = threadIdx.x >> 6;
  const int lane = threadIdx.x & 63;
  const int node = blockIdx.x*4 + wave;
  if (node >= N) return;
  const int s0 = start[node], s1 = start[node+1];
  float acc0 = 0.f, acc1 = 0.f;
  int e = s0;
  for (; e + 1 < s1; e += 2){
    int sA = csr[e], sB = csr[e+1];
    const float* ha = H + (size_t)sA*128;
    const float* hb = H + (size_t)sB*128;
    acc0 += ha[lane]; acc1 += ha[64+lane];
    acc0 += hb[lane]; acc1 += hb[64+lane];
  }
  if (e < s1){
    const float* ha = H + (size_t)csr[e]*128;
    acc0 += ha[lane]; acc1 += ha[64+lane];
  }
  Xout[(size_t)node*128 + lane] = acc0;
  Xout[(size_t)node*128 + 64 + lane] = acc1;

  // 13 head dot-products: [0]=Wc, [1..9]=WR, [10..12]=Wt
  float dsum[13];
  dsum[0] = acc0*Wc[lane] + acc1*Wc[64+lane];
#pragma unroll
  for (int c = 0; c < 9; c++)
    dsum[1+c] = acc0*WR[lane*9 + c] + acc1*WR[(64+lane)*9 + c];
#pragma unroll
  for (int c = 0; c < 3; c++)
    dsum[10+c] = acc0*Wt[lane*3 + c] + acc1*Wt[(64+lane)*3 + c];
#pragma unroll
  for (int c = 0; c < 13; c++){
    float v = dsum[c];
#pragma unroll
    for (int off = 32; off > 0; off >>= 1) v += __shfl_xor(v, off);
    dsum[c] = v;
  }

  if (lane == 0){
    double A[3][3], Q[3][3];
#pragma unroll
    for (int r = 0; r < 3; r++)
#pragma unroll
      for (int c = 0; c < 3; c++)
        A[r][c] = (double)dsum[1 + r*3 + c] + (double)bR[r*3 + c];
    qr3_q(A, Q);

    double pd = (double)dsum[0] + (double)bc[0];
#pragma unroll
    for (int c = 0; c < 3; c++){
      double base = (layer == 0) ? (double)pos_in[node*3 + c] : (double)pos_o[node*3 + c];
      pos_o[node*3 + c] = (float)(base + pd);
    }

    if (layer == 0){
#pragma unroll
      for (int r = 0; r < 3; r++)
#pragma unroll
        for (int c = 0; c < 3; c++)
          R_o[node*9 + r*3 + c] = (float)Q[r][c];
    } else {
      double Rold[3][3];
#pragma unroll
      for (int r = 0; r < 3; r++)
#pragma unroll
        for (int c = 0; c < 3; c++)
          Rold[r][c] = (double)R_o[node*9 + r*3 + c];
#pragma unroll
      for (int r = 0; r < 3; r++)
#pragma unroll
        for (int c = 0; c < 3; c++){
          double s = Q[r][0]*Rold[0][c] + Q[r][1]*Rold[1][c] + Q[r][2]*Rold[2][c];
          R_o[node*9 + r*3 + c] = (float)s;
        }
    }
#pragma unroll
    for (int c = 0; c < 3; c++){
      double base = (layer == 0) ? 0.0 : (double)t_o[node*3 + c];
      t_o[node*3 + c] = (float)(base + (double)dsum[10 + c] + (double)bt[c]);
    }
  }
}

extern "C" void kernel_launch(void* const* d_in, const int* in_sizes, int n_in,
                              void* d_out, int out_size, void* d_ws, size_t ws_size,
                              hipStream_t stream){
  const float* x0  = (const float*)d_in[0];
  const float* pos = (const float*)d_in[1];
  const int*   ei  = (const int*)d_in[2];
  const float* Wl  = (const float*)d_in[3];
  const float* bl  = (const float*)d_in[4];
  const float* Wc  = (const float*)d_in[5];
  const float* bc  = (const float*)d_in[6];
  const float* WR  = (const float*)d_in[7];
  const float* bR  = (const float*)d_in[8];
  const float* Wt  = (const float*)d_in[9];
  const float* bt  = (const float*)d_in[10];
  const float* Wf  = (const float*)d_in[11];
  const float* bf  = (const float*)d_in[12];

  const int N = in_sizes[0] / 128;
  const int E = in_sizes[2] / 2;
  const int* srcp = ei;
  const int* dstp = ei + E;

  float* z_out = (float*)d_out;
  float* pos_o = z_out + (size_t)N*128;
  float* R_o   = pos_o + (size_t)N*3;
  float* t_o   = R_o   + (size_t)N*9;

  char* ws = (char*)d_ws;
  size_t off = 0;
  auto alloc = [&](size_t bytes)->char*{
    char* p = ws + off; off += (bytes + 511) & ~(size_t)511; return p;
  };
  float* buf0   = (float*)alloc((size_t)N*128*4);   // x / out ping buffer
  float* buf1   = (float*)alloc((size_t)N*128*4);   // h buffer
  int*   startp = (int*)  alloc((size_t)(N+1)*4);
  int*   cursor = (int*)  alloc((size_t)N*4);
  int*   deg    = (int*)  alloc((size_t)N*4);
  int*   bsum   = (int*)  alloc(4096);
  int*   csr    = (int*)  alloc((size_t)E*4);

  hipMemsetAsync(deg, 0, (size_t)N*4, stream);
  const int nb = (N + 1023) / 1024;
  k_count<<<dim3((E+255)/256), dim3(256), 0, stream>>>(dstp, E, deg);
  k_scanA<<<dim3(nb), dim3(1024), 0, stream>>>(deg, N, startp, bsum);
  k_scanB<<<dim3(1), dim3(64), 0, stream>>>(bsum, nb, startp, N);
  k_scanC<<<dim3((N+255)/256), dim3(256), 0, stream>>>(startp, bsum, cursor, N);
  k_fill <<<dim3((E+255)/256), dim3(256), 0, stream>>>(srcp, dstp, E, cursor, csr);

  const float* x = x0;
  for (int layer = 0; layer < 3; layer++){
    k_gemm128<<<dim3((N+127)/128), dim3(256), 0, stream>>>(
        x, Wl + (size_t)layer*128*128, bl + (size_t)layer*128, buf1, N);
    k_agg<<<dim3((N+3)/4), dim3(256), 0, stream>>>(
        buf1, csr, startp, buf0,
        Wc + (size_t)layer*128, bc + layer,
        WR + (size_t)layer*128*9, bR + (size_t)layer*9,
        Wt + (size_t)layer*128*3, bt + (size_t)layer*3,
        pos, pos_o, R_o, t_o, layer, N);
    x = buf0;
  }
  k_gemm128<<<dim3((N+127)/128), dim3(256), 0, stream>>>(x, Wf, bf, z_out, N);
}

// Round 2
// 471.322 us; speedup vs baseline: 1.1810x; 1.1810x over previous
//
#include <hip/hip_runtime.h>
#include <hip/hip_fp16.h>

typedef _Float16 half8 __attribute__((ext_vector_type(8)));
typedef float floatx4 __attribute__((ext_vector_type(4)));

// ---------------- QR: 3x3 Householder, LAPACK sgeqrf/sorgqr convention ----------------
__device__ inline void qr3_q(const double A[3][3], double Q[3][3]){
  double a[3][3];
#pragma unroll
  for (int r = 0; r < 3; r++)
#pragma unroll
    for (int c = 0; c < 3; c++) a[r][c] = A[r][c];

  double v1[3] = {1.0, 0.0, 0.0};
  double tau1 = 0.0;
  {
    double xn2 = a[1][0]*a[1][0] + a[2][0]*a[2][0];
    if (xn2 != 0.0){
      double alpha = a[0][0];
      double beta = -copysign(sqrt(alpha*alpha + xn2), alpha);
      tau1 = (beta - alpha) / beta;
      double inv = 1.0 / (alpha - beta);
      v1[1] = a[1][0] * inv;
      v1[2] = a[2][0] * inv;
#pragma unroll
      for (int c = 1; c < 3; c++){
        double w = a[0][c] + v1[1]*a[1][c] + v1[2]*a[2][c];
        double tw = tau1 * w;
        a[0][c] -= tw;
        a[1][c] -= tw * v1[1];
        a[2][c] -= tw * v1[2];
      }
    }
  }
  double tau2 = 0.0, v2 = 0.0;
  {
    double x2 = a[2][1];
    if (x2 != 0.0){
      double alpha = a[1][1];
      double beta = -copysign(sqrt(alpha*alpha + x2*x2), alpha);
      tau2 = (beta - alpha) / beta;
      v2 = x2 / (alpha - beta);
    }
  }
  double M[3][3] = {{1.0, 0.0, 0.0},
                    {0.0, 1.0 - tau2, -tau2*v2},
                    {0.0, -tau2*v2, 1.0 - tau2*v2*v2}};
#pragma unroll
  for (int c = 0; c < 3; c++){
    double w = v1[0]*M[0][c] + v1[1]*M[1][c] + v1[2]*M[2][c];
#pragma unroll
    for (int r = 0; r < 3; r++)
      Q[r][c] = M[r][c] - tau1 * v1[r] * w;
  }
}

// ---------------- CSR build ----------------
__global__ void k_count(const int* __restrict__ dst, int E, int* __restrict__ deg){
  int e = blockIdx.x*256 + threadIdx.x;
  if (e < E) atomicAdd(&deg[dst[e]], 1);
}

__global__ void k_scanA(const int* __restrict__ deg, int N, int* __restrict__ start, int* __restrict__ bsum){
  __shared__ int s[1024];
  int t = threadIdx.x;
  int i = blockIdx.x*1024 + t;
  int v = (i < N) ? deg[i] : 0;
  s[t] = v;
  __syncthreads();
  for (int off = 1; off < 1024; off <<= 1){
    int add = (t >= off) ? s[t - off] : 0;
    __syncthreads();
    s[t] += add;
    __syncthreads();
  }
  if (i < N) start[i] = s[t] - v;
  if (t == 1023) bsum[blockIdx.x] = s[t];
}

__global__ void k_scanB(int* __restrict__ bsum, int nb, int* __restrict__ start, int N){
  if (threadIdx.x == 0 && blockIdx.x == 0){
    int run = 0;
    for (int j = 0; j < nb; j++){ int tv = bsum[j]; bsum[j] = run; run += tv; }
    start[N] = run;
  }
}

__global__ void k_scanC(int* __restrict__ start, const int* __restrict__ bsum, int* __restrict__ cursor, int N){
  int i = blockIdx.x*256 + threadIdx.x;
  if (i < N){
    int v = start[i] + bsum[i >> 10];
    start[i] = v;
    cursor[i] = v;
  }
}

__global__ void k_fill(const int* __restrict__ src, const int* __restrict__ dst, int E,
                       int* __restrict__ cursor, int* __restrict__ csr){
  int e = blockIdx.x*256 + threadIdx.x;
  if (e < E){
    int p = atomicAdd(&cursor[dst[e]], 1);
    csr[p] = src[e];
  }
}

// ---------------- prep: fp32 -> fp16 convert, W transpose+convert ----------------
__global__ void k_f2h(const float4* __restrict__ x, uint2* __restrict__ xh, int n4){
  int i = blockIdx.x*256 + threadIdx.x;
  if (i < n4){
    float4 v = x[i];
    __half2 a = __floats2half2_rn(v.x, v.y);
    __half2 b = __floats2half2_rn(v.z, v.w);
    uint2 o;
    o.x = *(unsigned int*)&a;
    o.y = *(unsigned int*)&b;
    xh[i] = o;
  }
}

// wT16[l][n][k] = W_l[k][n]; l in 0..2 -> Wl, l==3 -> Wf
__global__ void k_prep_w(const float* __restrict__ Wl, const float* __restrict__ Wf,
                         _Float16* __restrict__ wT16){
  int idx = blockIdx.x*256 + threadIdx.x;      // 4*128*128 = 65536
  int l = idx >> 14;
  int rem = idx & 16383;
  int n = rem >> 7;
  int k = rem & 127;
  const float* W = (l < 3) ? (Wl + (size_t)l*16384) : Wf;
  wT16[idx] = (_Float16)W[k*128 + n];
}

// ---------------- fp16 MFMA GEMM: H(Mx128) = X(Mx128) @ W(128x128) + bias ----------------
// A frag: A[m=lane&15][k=quad*8+j]  B frag: B[k=quad*8+j][n=lane&15] (from Wt row-major n-major)
// D frag: col=lane&15, row=quad*4+reg
__launch_bounds__(256)
__global__ void k_gemm_mfma(const _Float16* __restrict__ X, const _Float16* __restrict__ Wt,
                            const float* __restrict__ bias, void* __restrict__ Hout,
                            int M, int out_fp32){
  const int wave = threadIdx.x >> 6;
  const int lane = threadIdx.x & 63;
  const int quad = lane >> 4;
  const int l16  = lane & 15;
  const int r0 = blockIdx.x*128 + wave*32;

  floatx4 acc[2][8] = {};
#pragma unroll
  for (int kc = 0; kc < 4; kc++){
    half8 af[2];
#pragma unroll
    for (int rt = 0; rt < 2; rt++){
      int r = r0 + rt*16 + l16;
      r = (r < M) ? r : (M - 1);     // clamped rows only pollute unstored D rows
      af[rt] = *(const half8*)(X + (size_t)r*128 + kc*32 + quad*8);
    }
#pragma unroll
    for (int ct = 0; ct < 8; ct++){
      half8 bf = *(const half8*)(Wt + (size_t)(ct*16 + l16)*128 + kc*32 + quad*8);
      acc[0][ct] = __builtin_amdgcn_mfma_f32_16x16x32_f16(af[0], bf, acc[0][ct], 0, 0, 0);
      acc[1][ct] = __builtin_amdgcn_mfma_f32_16x16x32_f16(af[1], bf, acc[1][ct], 0, 0, 0);
    }
  }
#pragma unroll
  for (int rt = 0; rt < 2; rt++){
#pragma unroll
    for (int ct = 0; ct < 8; ct++){
      int col = ct*16 + l16;
      float bv = bias[col];
#pragma unroll
      for (int reg = 0; reg < 4; reg++){
        int r = r0 + rt*16 + quad*4 + reg;
        if (r < M){
          float v = acc[rt][ct][reg] + bv;
          if (out_fp32) ((float*)Hout)[(size_t)r*128 + col] = v;
          else          ((_Float16*)Hout)[(size_t)r*128 + col] = (_Float16)v;
        }
      }
    }
  }
}

// ---------------- fused aggregation (fp16 CSR gather) + heads + QR + pos/R/t ----------------
__launch_bounds__(256)
__global__ void k_agg(const _Float16* __restrict__ H, const int* __restrict__ csr,
                      const int* __restrict__ start, _Float16* __restrict__ Xout,
                      const float* __restrict__ Wc, const float* __restrict__ bc,
                      const float* __restrict__ WR, const float* __restrict__ bR,
                      const float* __restrict__ Wt, const float* __restrict__ bt,
                      const float* __restrict__ pos_in,
                      float* __restrict__ pos_o, float* __restrict__ R_o, float* __restrict__ t_o,
                      int layer, int N){
  const int wave = threadIdx.x >> 6;
  const int lane = threadIdx.x & 63;
  const int node = blockIdx.x*4 + wave;
  if (node >= N) return;
  const int s0 = start[node], s1 = start[node+1];
  const unsigned int* Hu = (const unsigned int*)H;   // half2 per uint; row = 64 uints
  float acc0 = 0.f, acc1 = 0.f;
  int e = s0;
  for (; e + 3 < s1; e += 4){
    unsigned int v0 = Hu[(size_t)csr[e]  *64 + lane];
    unsigned int v1 = Hu[(size_t)csr[e+1]*64 + lane];
    unsigned int v2 = Hu[(size_t)csr[e+2]*64 + lane];
    unsigned int v3 = Hu[(size_t)csr[e+3]*64 + lane];
    float2 f0 = __half22float2(*(__half2*)&v0);
    float2 f1 = __half22float2(*(__half2*)&v1);
    float2 f2 = __half22float2(*(__half2*)&v2);
    float2 f3 = __half22float2(*(__half2*)&v3);
    acc0 += (f0.x + f1.x) + (f2.x + f3.x);
    acc1 += (f0.y + f1.y) + (f2.y + f3.y);
  }
  for (; e < s1; e++){
    unsigned int v = Hu[(size_t)csr[e]*64 + lane];
    float2 f = __half22float2(*(__half2*)&v);
    acc0 += f.x; acc1 += f.y;
  }
  __half2 ho = __floats2half2_rn(acc0, acc1);
  ((unsigned int*)Xout)[(size_t)node*64 + lane] = *(unsigned int*)&ho;

  // heads: this lane holds out elements i0=2*lane, i1=2*lane+1
  const int i0 = 2*lane, i1 = 2*lane + 1;
  float dsum[13];
  dsum[0] = acc0*Wc[i0] + acc1*Wc[i1];
#pragma unroll
  for (int c = 0; c < 9; c++)
    dsum[1+c] = acc0*WR[i0*9 + c] + acc1*WR[i1*9 + c];
#pragma unroll
  for (int c = 0; c < 3; c++)
    dsum[10+c] = acc0*Wt[i0*3 + c] + acc1*Wt[i1*3 + c];
#pragma unroll
  for (int c = 0; c < 13; c++){
    float v = dsum[c];
#pragma unroll
    for (int off = 32; off > 0; off >>= 1) v += __shfl_xor(v, off);
    dsum[c] = v;
  }

  if (lane == 0){
    double A[3][3], Q[3][3];
#pragma unroll
    for (int r = 0; r < 3; r++)
#pragma unroll
      for (int c = 0; c < 3; c++)
        A[r][c] = (double)dsum[1 + r*3 + c] + (double)bR[r*3 + c];
    qr3_q(A, Q);

    double pd = (double)dsum[0] + (double)bc[0];
#pragma unroll
    for (int c = 0; c < 3; c++){
      double base = (layer == 0) ? (double)pos_in[node*3 + c] : (double)pos_o[node*3 + c];
      pos_o[node*3 + c] = (float)(base + pd);
    }

    if (layer == 0){
#pragma unroll
      for (int r = 0; r < 3; r++)
#pragma unroll
        for (int c = 0; c < 3; c++)
          R_o[node*9 + r*3 + c] = (float)Q[r][c];
    } else {
      double Rold[3][3];
#pragma unroll
      for (int r = 0; r < 3; r++)
#pragma unroll
        for (int c = 0; c < 3; c++)
          Rold[r][c] = (double)R_o[node*9 + r*3 + c];
#pragma unroll
      for (int r = 0; r < 3; r++)
#pragma unroll
        for (int c = 0; c < 3; c++){
          double s = Q[r][0]*Rold[0][c] + Q[r][1]*Rold[1][c] + Q[r][2]*Rold[2][c];
          R_o[node*9 + r*3 + c] = (float)s;
        }
    }
#pragma unroll
    for (int c = 0; c < 3; c++){
      double base = (layer == 0) ? 0.0 : (double)t_o[node*3 + c];
      t_o[node*3 + c] = (float)(base + (double)dsum[10 + c] + (double)bt[c]);
    }
  }
}

extern "C" void kernel_launch(void* const* d_in, const int* in_sizes, int n_in,
                              void* d_out, int out_size, void* d_ws, size_t ws_size,
                              hipStream_t stream){
  const float* x0  = (const float*)d_in[0];
  const float* pos = (const float*)d_in[1];
  const int*   ei  = (const int*)d_in[2];
  const float* Wl  = (const float*)d_in[3];
  const float* bl  = (const float*)d_in[4];
  const float* Wc  = (const float*)d_in[5];
  const float* bc  = (const float*)d_in[6];
  const float* WR  = (const float*)d_in[7];
  const float* bR  = (const float*)d_in[8];
  const float* Wt  = (const float*)d_in[9];
  const float* bt  = (const float*)d_in[10];
  const float* Wf  = (const float*)d_in[11];
  const float* bf  = (const float*)d_in[12];

  const int N = in_sizes[0] / 128;
  const int E = in_sizes[2] / 2;
  const int* srcp = ei;
  const int* dstp = ei + E;

  float* z_out = (float*)d_out;
  float* pos_o = z_out + (size_t)N*128;
  float* R_o   = pos_o + (size_t)N*3;
  float* t_o   = R_o   + (size_t)N*9;

  char* ws = (char*)d_ws;
  size_t off = 0;
  auto alloc = [&](size_t bytes)->char*{
    char* p = ws + off; off += (bytes + 511) & ~(size_t)511; return p;
  };
  _Float16* buf0h = (_Float16*)alloc((size_t)N*128*2);   // x16 / out16 ping
  _Float16* buf1h = (_Float16*)alloc((size_t)N*128*2);   // h16 buffer
  _Float16* wT16  = (_Float16*)alloc((size_t)4*128*128*2);
  int* startp = (int*)alloc((size_t)(N+1)*4);
  int* cursor = (int*)alloc((size_t)N*4);
  int* deg    = (int*)alloc((size_t)N*4);
  int* bsum   = (int*)alloc(4096);
  int* csr    = (int*)alloc((size_t)E*4);

  hipMemsetAsync(deg, 0, (size_t)N*4, stream);
  const int nb = (N + 1023) / 1024;
  k_count<<<dim3((E+255)/256), dim3(256), 0, stream>>>(dstp, E, deg);
  k_scanA<<<dim3(nb), dim3(1024), 0, stream>>>(deg, N, startp, bsum);
  k_scanB<<<dim3(1), dim3(64), 0, stream>>>(bsum, nb, startp, N);
  k_scanC<<<dim3((N+255)/256), dim3(256), 0, stream>>>(startp, bsum, cursor, N);
  k_fill <<<dim3((E+255)/256), dim3(256), 0, stream>>>(srcp, dstp, E, cursor, csr);

  // prep fp16 operands
  k_f2h   <<<dim3((N*128/4 + 255)/256), dim3(256), 0, stream>>>((const float4*)x0, (uint2*)buf0h, N*128/4);
  k_prep_w<<<dim3(65536/256), dim3(256), 0, stream>>>(Wl, Wf, wT16);

  const int gemm_blocks = (N + 127)/128;
  const _Float16* xcur = buf0h;
  for (int layer = 0; layer < 3; layer++){
    k_gemm_mfma<<<dim3(gemm_blocks), dim3(256), 0, stream>>>(
        xcur, wT16 + (size_t)layer*16384, bl + (size_t)layer*128, (void*)buf1h, N, 0);
    k_agg<<<dim3((N+3)/4), dim3(256), 0, stream>>>(
        buf1h, csr, startp, buf0h,
        Wc + (size_t)layer*128, bc + layer,
        WR + (size_t)layer*128*9, bR + (size_t)layer*9,
        Wt + (size_t)layer*128*3, bt + (size_t)layer*3,
        pos, pos_o, R_o, t_o, layer, N);
    xcur = buf0h;
  }
  k_gemm_mfma<<<dim3(gemm_blocks), dim3(256), 0, stream>>>(
      xcur, wT16 + (size_t)3*16384, bf, (void*)z_out, N, 1);
}